// Round 3
// baseline (3581.607 us; speedup 1.0000x reference)
//
#include <hip/hip_runtime.h>

// WaveNet fused, fp32. Dilation fixed at 1024 => t = r + 1024*s decomposes into
// 8192 independent chains (b,r) of 16 steps x 32 channels.
// Persistent cooperative kernel (512 blocks, 2 tiles of 8 chains each) runs all
// 40 layers with h in LDS, skip in VGPRs; per-layer BN stats via spread device
// atomics + leaf/root/done spin barrier. Coop launch return code is CHECKED,
// falling back to a plain launch (512 blocks at 3-blocks/CU capacity 768).
// ws (floats): h [8192][32][16] @0, skip @4M, small stats @8M.
// d_out head region (dead until k_ep_c) holds per-layer z-stats + counters.

#define EPSV 1e-5f
#define RN   (1.f/131072.f)

#define H_OFF  0
#define SK_OFF (4*1024*1024)
#define ST_OFF (8*1024*1024)
#define ST_SKIP 2560   // skip sum[32], sumsq[32]
#define ST_MU   2624   // y1 mean-sum [32]
#define ST_Y    2656   // y1 second-moment sums [32][32]
#define ST_A2   3680   // bn2 scale [256]
#define ST_B2   3936   // bn2 shift [256]
#define ST_TOT  4192

// scratch in d_out (elements): z-stats spread 1 line per value, then counters
#define SZ_STAT (40*4096)             // layer L, ch c: sum @ L*4096+c*64, sq @ +32
#define CTR0    SZ_STAT               // leaf counters: (L*16+leaf)*32
#define ROOT0   (CTR0 + 40*16*32)
#define DONE0   (ROOT0 + 40*32)
#define SCR_TOT (DONE0 + 40*32)       // = 186880 = 730*256

#define NBLK 512

__device__ __forceinline__ float rcp_f(float x) { return __builtin_amdgcn_rcpf(x); }
__device__ __forceinline__ float tanh_f(float x) {
    float e = __expf(2.f * x);
    return 1.f - 2.f * rcp_f(e + 1.f);
}
__device__ __forceinline__ float sigm_f(float x) { return rcp_f(1.f + __expf(-x)); }
__device__ __forceinline__ float mish_f(float x) {
    float e = __expf(x);
    float sp = (x > 15.f) ? x : __logf(1.f + e);
    return x * tanh_f(sp);
}

// ---------------- zero stats + scratch (everything is poisoned 0xAA) ---------
__global__ void k_zero(float* __restrict__ st, float* __restrict__ scr) {
    int i = blockIdx.x * 256 + threadIdx.x;
    if (i < SCR_TOT) scr[i] = 0.f;
    if (i < ST_TOT)  st[i]  = 0.f;
}

// ---------------- start conv: h = W_s @ shift_right(x,1) + b_s ----------------
__global__ __launch_bounds__(256) void k_start(
        const float* __restrict__ x, const float* __restrict__ sw_g,
        const float* __restrict__ sb_g, float* __restrict__ h)
{
    __shared__ float sw[256*36];
    __shared__ float sb[32];
    int tid = threadIdx.x, blk = blockIdx.x;
    int b = blk >> 6, r0 = (blk & 63) << 4;
    for (int k = tid; k < 8192; k += 256) {
        int o = k >> 8, c = k & 255;
        sw[c*36 + o] = sw_g[k];
    }
    if (tid < 32) sb[tid] = sb_g[tid];
    __syncthreads();

    int rr = tid & 15, s = tid >> 4;
    int t = r0 + rr + (s << 10);
    bool valid = (t >= 1);
    const float* xr = x + (long)b*256*16384 + (valid ? (t-1) : 0);
    float acc[32];
    #pragma unroll
    for (int o = 0; o < 32; ++o) acc[o] = 0.f;
    for (int c = 0; c < 256; ++c) {
        float xv = xr[(long)c*16384];
        xv = valid ? xv : 0.f;
        const float4* wrow = (const float4*)&sw[c*36];
        #pragma unroll
        for (int o4 = 0; o4 < 8; ++o4) {
            float4 w = wrow[o4];
            acc[o4*4+0] += w.x*xv; acc[o4*4+1] += w.y*xv;
            acc[o4*4+2] += w.z*xv; acc[o4*4+3] += w.w*xv;
        }
    }
    __syncthreads();
    #pragma unroll
    for (int o = 0; o < 32; ++o) sw[(rr*32 + o)*16 + s] = acc[o] + sb[o];
    __syncthreads();
    float4* hd = (float4*)(h + (long)blk*8192);
    const float4* ss = (const float4*)sw;
    for (int k = tid; k < 2048; k += 256) hd[k] = ss[k];
}

// ---------------- persistent layer kernel (512 blocks, 2 tiles each) ----------
// block = 256 thr = 8 chains x 32 ch, two tiles processed serially per layer.
// LDS: s_h 32KB (both tiles, persistent) + s_wg 16KB (gate weights / g staging)
//      + s_r 4KB + s_red 1KB = 53KB -> 3 blocks/CU capacity (768 >= 512).
__global__ __launch_bounds__(256, 3) void k_layers(
        const float* __restrict__ gt_w, const float* __restrict__ gt_b,
        const float* __restrict__ gs_w, const float* __restrict__ gs_b,
        const float* __restrict__ res_w, const float* __restrict__ res_b,
        const float* __restrict__ bn_g, const float* __restrict__ bn_b,
        const float* __restrict__ h, float* __restrict__ skip,
        float* __restrict__ scr, float* __restrict__ st)
{
    __shared__ float s_h[8192];      // [t][chl][o][16]
    __shared__ float s_wg[4096];     // gate weights [i][o][4]; reused as g staging
    __shared__ float s_r[1024];      // [i][o]
    __shared__ float s_red[4][32][2];
    unsigned* ctr = (unsigned*)scr;

    int tid = threadIdx.x;
    int o = tid & 31, chl = tid >> 5, wv = tid >> 6;
    long base = (long)blockIdx.x*8192 + chl*512 + o*16;

    #pragma unroll
    for (int t = 0; t < 2; ++t) {    // load both tiles' h into LDS
        const float4* hp4 = (const float4*)(h + base + t*4096);
        float4* hs4 = (float4*)&s_h[t*4096 + chl*512 + o*16];
        #pragma unroll
        for (int q = 0; q < 4; ++q) hs4[q] = hp4[q];
    }
    float sk[2][16];
    #pragma unroll
    for (int t = 0; t < 2; ++t)
        #pragma unroll
        for (int s = 0; s < 16; ++s) sk[t][s] = 0.f;

    for (int L = 0; L < 40; ++L) {
        // 1. stage weights: gt_w/gs_w [L][o][i][2], res_w [L][o][i]
        for (int k = tid; k < 1024; k += 256) {
            int oo = k >> 5, ii = k & 31;
            float2 a = ((const float2*)(gt_w + (long)L*2048))[k];
            float2 c = ((const float2*)(gs_w + (long)L*2048))[k];
            float* d = &s_wg[(ii*32 + oo)*4];
            d[0] = a.x; d[1] = a.y; d[2] = c.x; d[3] = c.y;
            s_r[ii*32 + oo] = res_w[(long)L*1024 + k];
        }
        __syncthreads();

        // 2. gate matvecs for both tiles (weights stay resident)
        float g0[16], g1[16];
        float gtb = gt_b[L*32 + o], gsb = gs_b[L*32 + o];
        #pragma unroll
        for (int t = 0; t < 2; ++t) {
            float aT[16], aS[16];
            #pragma unroll
            for (int s = 0; s < 16; ++s) { aT[s] = gtb; aS[s] = gsb; }
            #pragma unroll 4
            for (int i = 0; i < 32; ++i) {
                float4 w = *(const float4*)&s_wg[(i*32 + o)*4];
                const float4* hr = (const float4*)&s_h[t*4096 + chl*512 + i*16];
                float hp = 0.f;                   // s=0 shifted tap is zero-pad
                #pragma unroll
                for (int s4 = 0; s4 < 4; ++s4) {
                    float4 hv = hr[s4];
                    int s = 4*s4;
                    aT[s+0] += w.y*hv.x + w.x*hp;   aS[s+0] += w.w*hv.x + w.z*hp;
                    aT[s+1] += w.y*hv.y + w.x*hv.x; aS[s+1] += w.w*hv.y + w.z*hv.x;
                    aT[s+2] += w.y*hv.z + w.x*hv.y; aS[s+2] += w.w*hv.z + w.z*hv.y;
                    aT[s+3] += w.y*hv.w + w.x*hv.z; aS[s+3] += w.w*hv.w + w.z*hv.z;
                    hp = hv.w;
                }
            }
            float* gd = t ? g1 : g0;
            #pragma unroll
            for (int s = 0; s < 16; ++s) {
                gd[s] = tanh_f(aT[s]) * sigm_f(aS[s]);
                sk[t][s] += gd[s];
            }
        }
        __syncthreads();                 // everyone done reading gate weights

        // 3/4. per tile: stage g over weight buffer, z = R @ g + rb
        float az[2][16];
        float rbv = res_b[L*32 + o];
        float ps = 0.f, pq = 0.f;
        #pragma unroll
        for (int t = 0; t < 2; ++t) {
            const float* gsrc = t ? g1 : g0;
            float4* gw = (float4*)&s_wg[chl*512 + o*16];
            #pragma unroll
            for (int q = 0; q < 4; ++q)
                gw[q] = make_float4(gsrc[4*q], gsrc[4*q+1], gsrc[4*q+2], gsrc[4*q+3]);
            __syncthreads();
            #pragma unroll
            for (int s = 0; s < 16; ++s) az[t][s] = rbv;
            #pragma unroll 4
            for (int i = 0; i < 32; ++i) {
                float w = s_r[i*32 + o];
                const float4* gr = (const float4*)&s_wg[chl*512 + i*16];
                #pragma unroll
                for (int s4 = 0; s4 < 4; ++s4) {
                    float4 gv = gr[s4];
                    az[t][4*s4+0] += w*gv.x; az[t][4*s4+1] += w*gv.y;
                    az[t][4*s4+2] += w*gv.z; az[t][4*s4+3] += w*gv.w;
                }
            }
            #pragma unroll
            for (int s = 0; s < 16; ++s) { ps += az[t][s]; pq += az[t][s]*az[t][s]; }
            __syncthreads();             // reads of s_wg done before next overwrite
        }

        // 5. z stats -> spread atomics
        ps += __shfl_down(ps, 32); pq += __shfl_down(pq, 32);
        if ((tid & 63) < 32) { s_red[wv][o][0] = ps; s_red[wv][o][1] = pq; }
        __syncthreads();
        if (tid < 32) {
            float a_ = s_red[0][tid][0] + s_red[1][tid][0] + s_red[2][tid][0] + s_red[3][tid][0];
            atomicAdd(&scr[(long)L*4096 + tid*64], a_);
            __threadfence();
        } else if (tid < 64) {
            int c = tid - 32;
            float a_ = s_red[0][c][1] + s_red[1][c][1] + s_red[2][c][1] + s_red[3][c][1];
            atomicAdd(&scr[(long)L*4096 + c*64 + 32], a_);
            __threadfence();
        }
        __syncthreads();                 // all block's atomics drained (vmcnt 0)

        // 6. grid barrier: leaf -> root -> done
        if (tid == 0) {
            int leaf = blockIdx.x & 15;
            unsigned old = __hip_atomic_fetch_add(&ctr[CTR0 + (L*16 + leaf)*32], 1u,
                                                  __ATOMIC_ACQ_REL, __HIP_MEMORY_SCOPE_AGENT);
            if (old == (NBLK/16 - 1)) {
                unsigned r = __hip_atomic_fetch_add(&ctr[ROOT0 + L*32], 1u,
                                                    __ATOMIC_ACQ_REL, __HIP_MEMORY_SCOPE_AGENT);
                if (r == 15)
                    __hip_atomic_store(&ctr[DONE0 + L*32], 1u,
                                       __ATOMIC_RELEASE, __HIP_MEMORY_SCOPE_AGENT);
            }
            while (__hip_atomic_load(&ctr[DONE0 + L*32],
                                     __ATOMIC_ACQUIRE, __HIP_MEMORY_SCOPE_AGENT) == 0u)
                __builtin_amdgcn_s_sleep(8);
        }
        __syncthreads();

        // 7. apply bn(z) to h in LDS
        float ssum = __hip_atomic_load(&scr[(long)L*4096 + o*64],
                                       __ATOMIC_RELAXED, __HIP_MEMORY_SCOPE_AGENT);
        float ssq  = __hip_atomic_load(&scr[(long)L*4096 + o*64 + 32],
                                       __ATOMIC_RELAXED, __HIP_MEMORY_SCOPE_AGENT);
        float m = ssum * RN;
        float v = ssq * RN - m*m;
        float a = rsqrtf(v + EPSV) * bn_g[L*32 + o];
        float bb = bn_b[L*32 + o] - m*a;
        #pragma unroll
        for (int t = 0; t < 2; ++t) {
            float* hrow = &s_h[t*4096 + chl*512 + o*16];
            #pragma unroll
            for (int s = 0; s < 16; ++s) hrow[s] += az[t][s]*a + bb;
        }
        // loop-top staging sync fences s_h/s_wg reuse
    }

    // skip stats (for bn1) + write skip to HBM
    float p2 = 0.f, q2 = 0.f;
    #pragma unroll
    for (int t = 0; t < 2; ++t)
        #pragma unroll
        for (int s = 0; s < 16; ++s) { p2 += sk[t][s]; q2 += sk[t][s]*sk[t][s]; }
    p2 += __shfl_down(p2, 32); q2 += __shfl_down(q2, 32);
    __syncthreads();
    if ((tid & 63) < 32) { s_red[wv][o][0] = p2; s_red[wv][o][1] = q2; }
    __syncthreads();
    if (tid < 32) {
        float a_ = s_red[0][tid][0] + s_red[1][tid][0] + s_red[2][tid][0] + s_red[3][tid][0];
        atomicAdd(&st[ST_SKIP + tid], a_);
    } else if (tid < 64) {
        int c = tid - 32;
        float a_ = s_red[0][c][1] + s_red[1][c][1] + s_red[2][c][1] + s_red[3][c][1];
        atomicAdd(&st[ST_SKIP + 32 + c], a_);
    }
    #pragma unroll
    for (int t = 0; t < 2; ++t) {
        float4* skp = (float4*)(skip + base + t*4096);
        #pragma unroll
        for (int q = 0; q < 4; ++q)
            skp[q] = make_float4(sk[t][4*q], sk[t][4*q+1], sk[t][4*q+2], sk[t][4*q+3]);
    }
}

// ---------------- epilogue A: y1 = mish(bn1(skip)); mean + 2nd moments --------
__global__ __launch_bounds__(256) void k_ep_a(
        const float* __restrict__ skip, const float* __restrict__ bn1_g,
        const float* __restrict__ bn1_b, float* __restrict__ st)
{
    __shared__ float sy[256*33];
    __shared__ float sA[32], sB[32];
    int tid = threadIdx.x;
    long cb = (long)blockIdx.x * 8192;
    if (tid < 32) {
        float ssum = st[ST_SKIP + tid], ssq = st[ST_SKIP + 32 + tid];
        float m = ssum * RN, v = ssq * RN - m*m;
        float a = rsqrtf(v + EPSV) * bn1_g[tid];
        sA[tid] = a; sB[tid] = bn1_b[tid] - m*a;
    }
    __syncthreads();
    for (int k = tid; k < 8192; k += 256) {
        int i = k & 31, p = k >> 5;
        int rr = p & 15, s = p >> 4;
        float v = skip[cb + rr*512 + i*16 + s];
        sy[p*33 + i] = mish_f(v * sA[i] + sB[i]);
    }
    __syncthreads();
    if (tid < 32) {
        float mu = 0.f;
        for (int p = 0; p < 256; ++p) mu += sy[p*33 + tid];
        atomicAdd(&st[ST_MU + tid], mu);
    }
    int jj = tid & 31, i0 = tid >> 5;
    float a0 = 0.f, a1 = 0.f, a2 = 0.f, a3 = 0.f;
    for (int p = 0; p < 256; ++p) {
        float yj = sy[p*33 + jj];
        a0 += yj * sy[p*33 + i0];
        a1 += yj * sy[p*33 + i0 + 8];
        a2 += yj * sy[p*33 + i0 + 16];
        a3 += yj * sy[p*33 + i0 + 24];
    }
    atomicAdd(&st[ST_Y + (i0     )*32 + jj], a0);
    atomicAdd(&st[ST_Y + (i0 +  8)*32 + jj], a1);
    atomicAdd(&st[ST_Y + (i0 + 16)*32 + jj], a2);
    atomicAdd(&st[ST_Y + (i0 + 24)*32 + jj], a3);
}

// ---------------- epilogue B: analytic bn2 stats ------------------------------
__global__ void k_ep_b(
        const float* __restrict__ e1_w, const float* __restrict__ e1_b,
        const float* __restrict__ bn2_g, const float* __restrict__ bn2_b,
        float* __restrict__ st)
{
    __shared__ float mu[32];
    int o = threadIdx.x;
    if (o < 32) mu[o] = st[ST_MU + o] * RN;
    __syncthreads();
    float w[32];
    const float4* wr = (const float4*)(e1_w + o*32);
    #pragma unroll
    for (int q = 0; q < 8; ++q) {
        float4 t4 = wr[q];
        w[4*q]=t4.x; w[4*q+1]=t4.y; w[4*q+2]=t4.z; w[4*q+3]=t4.w;
    }
    float m2 = e1_b[o];
    #pragma unroll
    for (int i = 0; i < 32; ++i) m2 += w[i]*mu[i];
    float var = 0.f;
    for (int i = 0; i < 32; ++i) {
        float wi = w[i], mi = mu[i];
        for (int j = 0; j < 32; ++j)
            var += wi * w[j] * (st[ST_Y + i*32 + j]*RN - mi*mu[j]);
    }
    float a2 = rsqrtf(var + EPSV) * bn2_g[o];
    st[ST_A2 + o] = a2;
    st[ST_B2 + o] = bn2_b[o] - m2*a2;
}

// ---------------- epilogue C: out = e2 @ mish(bn2(e1 @ mish(bn1(skip)))) + b --
// grid 4096: blk = id>>3 picks (b, r-group), st8 = id&7 picks 32-pos subtile.
__global__ __launch_bounds__(256, 4) void k_ep_c(
        const float* __restrict__ skip,
        const float* __restrict__ bn1_g, const float* __restrict__ bn1_b,
        const float* __restrict__ e1_w, const float* __restrict__ e1_b,
        const float* __restrict__ e2_w, const float* __restrict__ e2_b,
        const float* __restrict__ st, float* __restrict__ out)
{
    __shared__ float y1l[32*32];
    __shared__ float y2l[256*36];
    __shared__ float sA[32], sB[32];
    int tid = threadIdx.x;
    int blk = blockIdx.x >> 3, st8 = blockIdx.x & 7;
    int b = blk >> 6, r0 = (blk & 63) << 4;
    long cb = (long)blk * 8192;
    if (tid < 32) {
        float ssum = st[ST_SKIP + tid], ssq = st[ST_SKIP + 32 + tid];
        float m = ssum * RN, v = ssq * RN - m*m;
        float a = rsqrtf(v + EPSV) * bn1_g[tid];
        sA[tid] = a; sB[tid] = bn1_b[tid] - m*a;
    }
    float w1[32];
    {
        const float4* wr = (const float4*)(e1_w + tid*32);
        #pragma unroll
        for (int q = 0; q < 8; ++q) {
            float4 t4 = wr[q];
            w1[4*q]=t4.x; w1[4*q+1]=t4.y; w1[4*q+2]=t4.z; w1[4*q+3]=t4.w;
        }
    }
    float a2 = st[ST_A2 + tid], b2 = st[ST_B2 + tid];
    float eb1 = e1_b[tid];
    float eb2 = e2_b[tid];
    const float4* w2row = (const float4*)(e2_w + (long)tid * 256);
    __syncthreads();

    // phase A: y1 (32 i x 32 q), positions q = sl*16+rr, s = st8*2+sl
    for (int k = tid; k < 1024; k += 256) {
        int i = k >> 5, q = k & 31;
        int rr = q & 15, sl = q >> 4;
        float v = skip[cb + rr*512 + i*16 + st8*2 + sl];
        y1l[i*32 + q] = mish_f(v * sA[i] + sB[i]);
    }
    __syncthreads();
    // phase B: z2 = e1@y1, y2 = mish(bn2(z2)) -> LDS
    #pragma unroll 2
    for (int q4 = 0; q4 < 8; ++q4) {
        float4 acc = make_float4(eb1, eb1, eb1, eb1);
        #pragma unroll 8
        for (int i = 0; i < 32; ++i) {
            float4 yv = *(const float4*)&y1l[i*32 + q4*4];
            float wi = w1[i];
            acc.x += wi*yv.x; acc.y += wi*yv.y; acc.z += wi*yv.z; acc.w += wi*yv.w;
        }
        float4 y2v;
        y2v.x = mish_f(acc.x*a2 + b2);
        y2v.y = mish_f(acc.y*a2 + b2);
        y2v.z = mish_f(acc.z*a2 + b2);
        y2v.w = mish_f(acc.w*a2 + b2);
        *(float4*)&y2l[tid*36 + q4*4] = y2v;
    }
    __syncthreads();
    // phase C: out row = e2_w[tid,:] @ y2
    float acc[32];
    #pragma unroll
    for (int q = 0; q < 32; ++q) acc[q] = eb2;
    for (int i4 = 0; i4 < 64; ++i4) {
        float4 w4 = w2row[i4];
        float wa[4] = {w4.x, w4.y, w4.z, w4.w};
        #pragma unroll
        for (int ii = 0; ii < 4; ++ii) {
            float wv = wa[ii];
            const float* yr = &y2l[(i4*4 + ii)*36];
            #pragma unroll
            for (int q4 = 0; q4 < 8; ++q4) {
                float4 yv = *(const float4*)&yr[q4*4];
                acc[q4*4+0] += wv*yv.x; acc[q4*4+1] += wv*yv.y;
                acc[q4*4+2] += wv*yv.z; acc[q4*4+3] += wv*yv.w;
            }
        }
    }
    long ob = ((long)b*256 + tid)*16384 + (long)(st8*2)*1024 + r0;
    float4* op = (float4*)&out[ob];
    op[0] = make_float4(acc[0],  acc[1],  acc[2],  acc[3]);
    op[1] = make_float4(acc[4],  acc[5],  acc[6],  acc[7]);
    op[2] = make_float4(acc[8],  acc[9],  acc[10], acc[11]);
    op[3] = make_float4(acc[12], acc[13], acc[14], acc[15]);
    float4* op2 = (float4*)&out[ob + 1024];
    op2[0] = make_float4(acc[16], acc[17], acc[18], acc[19]);
    op2[1] = make_float4(acc[20], acc[21], acc[22], acc[23]);
    op2[2] = make_float4(acc[24], acc[25], acc[26], acc[27]);
    op2[3] = make_float4(acc[28], acc[29], acc[30], acc[31]);
}

extern "C" void kernel_launch(void* const* d_in, const int* in_sizes, int n_in,
                              void* d_out, int out_size, void* d_ws, size_t ws_size,
                              hipStream_t stream) {
    const float* x       = (const float*)d_in[0];
    const float* start_w = (const float*)d_in[1];
    const float* start_b = (const float*)d_in[2];
    const float* gt_w    = (const float*)d_in[3];
    const float* gt_b    = (const float*)d_in[4];
    const float* gs_w    = (const float*)d_in[5];
    const float* gs_b    = (const float*)d_in[6];
    const float* res_w   = (const float*)d_in[7];
    const float* res_b   = (const float*)d_in[8];
    const float* bn_g    = (const float*)d_in[9];
    const float* bn_b    = (const float*)d_in[10];
    const float* bn1_g   = (const float*)d_in[11];
    const float* bn1_b   = (const float*)d_in[12];
    const float* e1_w    = (const float*)d_in[13];
    const float* e1_b    = (const float*)d_in[14];
    const float* bn2_g   = (const float*)d_in[15];
    const float* bn2_b   = (const float*)d_in[16];
    const float* e2_w    = (const float*)d_in[17];
    const float* e2_b    = (const float*)d_in[18];
    float* ws  = (float*)d_ws;
    float* out = (float*)d_out;

    float* h    = ws + H_OFF;
    float* skip = ws + SK_OFF;
    float* st   = ws + ST_OFF;
    float* scr  = out;             // dead until k_ep_c overwrites all of out

    k_zero<<<dim3(730), dim3(256), 0, stream>>>(st, scr);
    k_start<<<dim3(512), dim3(256), 0, stream>>>(x, start_w, start_b, h);

    {
        const float* hc = h;
        void* kargs[12] = {
            (void*)&gt_w, (void*)&gt_b, (void*)&gs_w, (void*)&gs_b,
            (void*)&res_w, (void*)&res_b, (void*)&bn_g, (void*)&bn_b,
            (void*)&hc, (void*)&skip, (void*)&scr, (void*)&st };
        hipError_t rc = hipLaunchCooperativeKernel((const void*)k_layers,
                                                   dim3(NBLK), dim3(256),
                                                   kargs, 0, stream);
        if (rc != hipSuccess) {
            // capacity/capture rejection: plain launch (512 blocks fit at
            // 3 blocks/CU capacity 768 -> co-resident in practice)
            k_layers<<<dim3(NBLK), dim3(256), 0, stream>>>(
                gt_w, gt_b, gs_w, gs_b, res_w, res_b, bn_g, bn_b,
                h, skip, scr, st);
        }
    }

    k_ep_a<<<dim3(512), dim3(256), 0, stream>>>(skip, bn1_g, bn1_b, st);
    k_ep_b<<<dim3(1), dim3(256), 0, stream>>>(e1_w, e1_b, bn2_g, bn2_b, st);
    k_ep_c<<<dim3(4096), dim3(256), 0, stream>>>(skip, bn1_g, bn1_b, e1_w, e1_b,
                                                 e2_w, e2_b, st, out);
}